// Round 14
// baseline (11155.742 us; speedup 1.0000x reference)
//
#include <hip/hip_runtime.h>

#define Bb 32
#define Tt 512
#define Dd 256
#define Pp 512
#define Hh 512
#define G4 2048
#define TC 128   // time-chunk length (4 chunks)
#define NG 32    // groups: 1 batch each
#define WPG 4    // workgroups per group (grid = 128, 1024 thr/WG)

__device__ __forceinline__ float sigmf(float x){ return 1.0f/(1.0f+__expf(-x)); }
__device__ __forceinline__ float tanhf_(float x){ return 1.0f - 2.0f/(__expf(2.0f*x)+1.0f); }

typedef __attribute__((ext_vector_type(8))) short v8s;
typedef __attribute__((ext_vector_type(4))) float f32x4;

// out[m] = sum_k A[m,k]^2
__global__ void k_rowsq(const float* __restrict__ A, float* __restrict__ o, int M, int K){
  int m = blockIdx.x*blockDim.x + threadIdx.x;
  if (m >= M) return;
  const float4* a4 = (const float4*)(A + (size_t)m*K);
  float s = 0.f;
  for (int i = 0; i < K/4; ++i){ float4 v = a4[i]; s += v.x*v.x + v.y*v.y + v.z*v.z + v.w*v.w; }
  o[m] = s;
}

// out (N x M) = in (M x N)^T
__global__ void k_transpose(const float* __restrict__ in, float* __restrict__ out, int M, int N){
  __shared__ float tile[32][33];
  int bn = blockIdx.x * 32;
  int bm = blockIdx.y * 32;
  int tx = threadIdx.x, ty = threadIdx.y; // block (32,8)
  #pragma unroll
  for (int i = 0; i < 32; i += 8)
    tile[ty+i][tx] = in[(size_t)(bm+ty+i)*N + bn+tx];
  __syncthreads();
  #pragma unroll
  for (int i = 0; i < 32; i += 8)
    out[(size_t)(bn+ty+i)*M + bm+tx] = tile[tx][ty+i];
}

// bx[r] = dot(W_ih[r,:], b_lin) + b_ih[r] + b_hh[r]
__global__ void k_bx(const float* __restrict__ Wih, const float* __restrict__ blin,
                     const float* __restrict__ bih, const float* __restrict__ bhh,
                     float* __restrict__ bx){
  int r = blockIdx.x*blockDim.x + threadIdx.x; // 2048 threads
  const float4* w4 = (const float4*)(Wih + (size_t)r*Hh);
  const float4* b4 = (const float4*)blin;
  float s = 0.f;
  for (int i = 0; i < Hh/4; ++i){ float4 w=w4[i], b=b4[i]; s += w.x*b.x+w.y*b.y+w.z*b.z+w.w*b.w; }
  bx[r] = s + bih[r] + bhh[r];
}

// fp32 -> bf16 (RNE), 4 elems/thread
__global__ void k_cvt_bf16(const float* __restrict__ in, ushort* __restrict__ out, int n4){
  int i = blockIdx.x*blockDim.x + threadIdx.x;
  if (i >= n4) return;
  float4 v = ((const float4*)in)[i];
  ushort4 o;
  uint u;
  u = __float_as_uint(v.x); u += 0x7FFF + ((u>>16)&1); o.x = (ushort)(u>>16);
  u = __float_as_uint(v.y); u += 0x7FFF + ((u>>16)&1); o.y = (ushort)(u>>16);
  u = __float_as_uint(v.z); u += 0x7FFF + ((u>>16)&1); o.z = (ushort)(u>>16);
  u = __float_as_uint(v.w); u += 0x7FFF + ((u>>16)&1); o.w = (ushort)(u>>16);
  ((ushort4*)out)[i] = o;
}

// Generic tiled fp32 GEMM: C[M,N] = epi(A[M,K] @ B[K,N])
// EPI 0: none. EPI 1: exp(-max(rowAux[m]+colAux[n]-2*acc,0)).
// REMAP: A-row (and rowAux) index m -> (m>>7)*Tt + t0 + (m&127); C stays dense.
template<int EPI, bool REMAP>
__global__ __launch_bounds__(256) void k_gemm(const float* __restrict__ A, const float* __restrict__ Bm,
                                              float* __restrict__ C, int M, int N, int K,
                                              const float* __restrict__ rowAux,
                                              const float* __restrict__ colAux, int t0)
{
  __shared__ float As[16][132];
  __shared__ float Bs[16][68];
  const int tid = threadIdx.x;
  const int bm = blockIdx.x * 128;
  const int bn = blockIdx.y * 64;
  const int tm = (tid & 15) * 8;
  const int tn = (tid >> 4) * 4;
  const int arow = tid >> 1;
  const int akq  = (tid & 1) * 8;
  const int brow = tid >> 4;
  const int bcol = (tid & 15) * 4;
  const int am = bm + arow;
  const size_t aRow = REMAP ? ((size_t)(am >> 7) * Tt + t0 + (am & 127)) : (size_t)am;
  float acc[8][4] = {};
  for (int k0 = 0; k0 < K; k0 += 16){
    float4 a0 = *(const float4*)&A[aRow*K + k0 + akq];
    float4 a1 = *(const float4*)&A[aRow*K + k0 + akq + 4];
    float4 bv = *(const float4*)&Bm[(size_t)(k0 + brow)*N + bn + bcol];
    As[akq+0][arow]=a0.x; As[akq+1][arow]=a0.y; As[akq+2][arow]=a0.z; As[akq+3][arow]=a0.w;
    As[akq+4][arow]=a1.x; As[akq+5][arow]=a1.y; As[akq+6][arow]=a1.z; As[akq+7][arow]=a1.w;
    *(float4*)&Bs[brow][bcol] = bv;
    __syncthreads();
    #pragma unroll
    for (int kk = 0; kk < 16; ++kk){
      float4 x0 = *(const float4*)&As[kk][tm];
      float4 x1 = *(const float4*)&As[kk][tm+4];
      float4 y  = *(const float4*)&Bs[kk][tn];
      float av[8] = {x0.x,x0.y,x0.z,x0.w,x1.x,x1.y,x1.z,x1.w};
      #pragma unroll
      for (int i=0;i<8;++i){
        float a = av[i];
        acc[i][0] += a*y.x; acc[i][1] += a*y.y; acc[i][2] += a*y.z; acc[i][3] += a*y.w;
      }
    }
    __syncthreads();
  }
  #pragma unroll
  for (int i=0;i<8;++i){
    int m = bm + tm + i;
    size_t mAux = REMAP ? ((size_t)(m >> 7) * Tt + t0 + (m & 127)) : (size_t)m;
    float4 o;
    float vv[4];
    #pragma unroll
    for (int j=0;j<4;++j){
      int n = bn + tn + j;
      float v = acc[i][j];
      if (EPI==1) v = __expf(-fmaxf(rowAux[mAux] + colAux[n] - 2.f*v, 0.f));
      vv[j] = v;
    }
    o.x=vv[0]; o.y=vv[1]; o.z=vv[2]; o.w=vv[3];
    *(float4*)&C[(size_t)m*N + bn + tn] = o;
  }
}

// xs = feats(bf16)[M,K] @ Wx(bf16)[N,K]^T + bx[N], fp32 out. MFMA 16x16x32.
__global__ __launch_bounds__(256) void k_xs_mfma(
    const ushort* __restrict__ A, const ushort* __restrict__ Bm,
    const float* __restrict__ bx, float* __restrict__ C, int M, int N, int K)
{
  __shared__ ushort As[128][72];
  __shared__ ushort Ws[128][72];
  const int tid  = threadIdx.x;
  const int bm   = blockIdx.x * 128;
  const int bn   = blockIdx.y * 128;
  const int lane = tid & 63;
  const int w    = tid >> 6;
  const int wr   = w >> 1, wc = w & 1;
  const int srow = tid >> 1;
  const int scol = (tid & 1) * 32;
  const int fr   = lane & 15;
  const int fk   = (lane >> 4) * 8;

  f32x4 acc[4][4] = {};

  for (int k0 = 0; k0 < K; k0 += 64){
    const ushort* ag = &A [(size_t)(bm + srow)*K + k0 + scol];
    const ushort* wg = &Bm[(size_t)(bn + srow)*K + k0 + scol];
    #pragma unroll
    for (int q = 0; q < 4; ++q){
      *(v8s*)&As[srow][scol + q*8] = *(const v8s*)&ag[q*8];
      *(v8s*)&Ws[srow][scol + q*8] = *(const v8s*)&wg[q*8];
    }
    __syncthreads();
    #pragma unroll
    for (int kk = 0; kk < 64; kk += 32){
      v8s af[4], bf[4];
      #pragma unroll
      for (int mi = 0; mi < 4; ++mi)
        af[mi] = *(const v8s*)&As[wr*64 + mi*16 + fr][kk + fk];
      #pragma unroll
      for (int ni = 0; ni < 4; ++ni)
        bf[ni] = *(const v8s*)&Ws[wc*64 + ni*16 + fr][kk + fk];
      #pragma unroll
      for (int mi = 0; mi < 4; ++mi)
        #pragma unroll
        for (int ni = 0; ni < 4; ++ni)
          acc[mi][ni] = __builtin_amdgcn_mfma_f32_16x16x32_bf16(af[mi], bf[ni], acc[mi][ni], 0, 0, 0);
    }
    __syncthreads();
  }

  const int cr = lane >> 4;
  #pragma unroll
  for (int ni = 0; ni < 4; ++ni){
    const int n = bn + wc*64 + ni*16 + fr;
    const float bb = bx[n];
    #pragma unroll
    for (int mi = 0; mi < 4; ++mi){
      #pragma unroll
      for (int r = 0; r < 4; ++r){
        const int m = bm + wr*64 + mi*16 + cr*4 + r;
        C[(size_t)m*N + n] = acc[mi][ni][r] + bb;
      }
    }
  }
}

// ============================================================================
// Persistent LSTM — 4-producer sync groups (skew-reduction experiment).
// 32 groups (1 batch each) x 4 WGs x 1024 thr (grid 128). Group's 4 WGs land
// on one XCD (blockIdx = wg*32+gid -> %8 = gid%8). Per thread: W[8][32] = 256
// VGPR-floats (budget: 4 waves/SIMD x 512 unified VGPR+AGPR via
// amdgpu_waves_per_eu(4,4)). Inner structure is a strict r2 clone: same
// ks-slice layout, XOR-swizzled hbuf, shuffle ks-reduction, gate-gather over
// gsel lanes; per-(gate,j) summation order identical -> bitwise-same output.
// Sync = r13 sentinel-poll (out prefilled 0xFF = NaN; h-store IS the flag).
// One barrier/step: every wave has h-storing lanes, so a wave passing the
// poll implies all waves of all 4 WGs finished reading hbuf.
// ============================================================================
__global__ __launch_bounds__(1024) __attribute__((amdgpu_waves_per_eu(4, 4)))
void k_lstm_persist(const float* __restrict__ Whh, const float* __restrict__ xs,
                    float* __restrict__ cbuf, float* __restrict__ out, int t0)
{
  __shared__ float hbuf[Hh];       // 2 KB, swizzled (one batch)
  const int tid  = threadIdx.x;
  const int lane = tid & 63;
  const int gsel = tid & 3;
  const int ks   = (tid >> 2) & 15;
  const int ug   = tid >> 6;            // wave id 0..15
  const int gid  = blockIdx.x & 31;     // group = batch
  const int wg   = blockIdx.x >> 5;     // 0..3
  const int jbase = wg*128 + ug*8;
  const int b    = gid;

  // ---- load W: 8 gate-rows (gate gsel, j=jbase..jbase+7), k-slice [32ks,+32) ----
  float W[8][32];
  #pragma unroll
  for (int r = 0; r < 8; ++r){
    const float* wrow = &Whh[(size_t)(gsel*Hh + jbase + r)*Hh + ks*32];
    #pragma unroll
    for (int c = 0; c < 8; ++c){
      float4 w = *(const float4*)&wrow[c*4];
      W[r][c*4+0]=w.x; W[r][c*4+1]=w.y; W[r][c*4+2]=w.z; W[r][c*4+3]=w.w;
    }
  }

  // output identity: lanes with ks<8 own (gate gsel, j = jbase+ks)
  const int jown = jbase + (ks & 7);    // clamped for ks>=8 (redundant lanes)
  float c_st = (t0 == 0) ? 0.f : cbuf[(size_t)b*Hh + jown];

  // h-stage: 512 floats over first 128 threads (float4 each), swizzled
  const int skb = (tid & 127) * 4;
  const int ssw = skb ^ (((skb >> 5) & 7) << 2);
  const bool stager = (tid < 128);

  for (int tl = 0; tl < TC; ++tl){
    const int t = t0 + tl;

    // ---- stage h(t-1): sentinel-poll (data IS the flag), r13-proven ----
    if (stager){
      float4 hv = {0.f,0.f,0.f,0.f};
      if (t > 0){
        const unsigned long long* src =
          (const unsigned long long*)&out[((size_t)b*Tt + (t-1))*Hh + skb];
        unsigned long long a, c;
        for (;;){
          a = __hip_atomic_load(src+0, __ATOMIC_RELAXED, __HIP_MEMORY_SCOPE_AGENT);
          c = __hip_atomic_load(src+1, __ATOMIC_RELAXED, __HIP_MEMORY_SCOPE_AGENT);
          if ((unsigned)a != 0xFFFFFFFFu && (unsigned)(a>>32) != 0xFFFFFFFFu &&
              (unsigned)c != 0xFFFFFFFFu && (unsigned)(c>>32) != 0xFFFFFFFFu) break;
          __builtin_amdgcn_s_sleep(1);
        }
        hv.x = __uint_as_float((unsigned)a);
        hv.y = __uint_as_float((unsigned)(a>>32));
        hv.z = __uint_as_float((unsigned)c);
        hv.w = __uint_as_float((unsigned)(c>>32));
      }
      *(float4*)&hbuf[ssw] = hv;
    }
    __syncthreads();

    // ---- GEMV: 8 gate-rows x 32 k = 256 FMA, 8 ds_read_b128 ----
    float acc[8];
    #pragma unroll
    for (int r=0;r<8;++r) acc[r]=0.f;
    {
      const float* hb = &hbuf[ks*32];
      #pragma unroll
      for (int c = 0; c < 8; ++c){
        float4 h4 = *(const float4*)&hb[(c*4) ^ ((ks & 7) << 2)];
        #pragma unroll
        for (int r = 0; r < 8; ++r){
          acc[r] = fmaf(W[r][c*4+0], h4.x, acc[r]);
          acc[r] = fmaf(W[r][c*4+1], h4.y, acc[r]);
          acc[r] = fmaf(W[r][c*4+2], h4.z, acc[r]);
          acc[r] = fmaf(W[r][c*4+3], h4.w, acc[r]);
        }
      }
    }

    // ---- reduction over ks (lane bits 2-5), same tree as r2 ----
    #pragma unroll
    for (int m = 4; m <= 32; m <<= 1){
      #pragma unroll
      for (int r=0;r<8;++r)
        acc[r] += __shfl_xor(acc[r], m, 64);
    }
    // lane with ks = r (r<8) owns acc[r]
    float g = acc[0];
    #pragma unroll
    for (int r=1;r<8;++r)
      if (ks == r) g = acc[r];

    // ---- add xs, gather 4 gates (gsel lanes), update c,h ----
    g += xs[((size_t)b*TC + tl)*G4 + gsel*Hh + jown];
    const int lbase = lane & ~3;
    float gi = __shfl(g, lbase+0, 64);
    float gf = __shfl(g, lbase+1, 64);
    float gg = __shfl(g, lbase+2, 64);
    float go = __shfl(g, lbase+3, 64);
    gi = sigmf(gi); gf = sigmf(gf); gg = tanhf_(gg); go = sigmf(go);
    c_st = gf*c_st + gi*gg;
    float h = go * tanhf_(c_st);
    if (gsel == 0 && ks < 8)
      __hip_atomic_store(&out[((size_t)b*Tt + t)*Hh + jown], h,
                         __ATOMIC_RELAXED, __HIP_MEMORY_SCOPE_AGENT);
    // no trailing barrier: h(t) itself is the sync token (r13-proven)
  }
  if (gsel == 0 && ks < 8) cbuf[(size_t)b*Hh + jown] = c_st;
}

extern "C" void kernel_launch(void* const* d_in, const int* in_sizes, int n_in,
                              void* d_out, int out_size, void* d_ws, size_t ws_size,
                              hipStream_t stream)
{
  const float* x    = (const float*)d_in[0];
  const float* prot = (const float*)d_in[1];
  const float* Wlin = (const float*)d_in[2];
  const float* blin = (const float*)d_in[3];
  const float* Wih  = (const float*)d_in[4];
  const float* Whh  = (const float*)d_in[5];
  const float* bih  = (const float*)d_in[6];
  const float* bhh  = (const float*)d_in[7];
  float* out = (float*)d_out;
  float* ws  = (float*)d_ws;

  size_t off = 0;
  auto alloc = [&](size_t n)->float*{ float* p = ws + off; off += (n + 15) & ~((size_t)15); return p; };
  float* x2     = alloc((size_t)Bb*Tt);
  float* p2     = alloc(Pp);
  float* pT     = alloc((size_t)Dd*Pp);
  float* bx     = alloc(G4);
  float* Wx     = alloc((size_t)G4*Pp);
  ushort* WxB   = (ushort*)alloc((size_t)G4*Pp/2);
  float* cbuf   = alloc((size_t)Bb*Hh);
  float* featsC = alloc((size_t)Bb*TC*Pp);
  ushort* featsB= (ushort*)alloc((size_t)Bb*TC*Pp/2);
  float* xsC    = alloc((size_t)Bb*TC*G4);
  // total ~13.3M floats ~ 53 MB

  // ---- sentinel-fill out (0xFF bytes = NaN pattern per word), in-graph ----
  hipMemsetAsync(out, 0xFF, (size_t)Bb*Tt*Hh*sizeof(float), stream);

  // ---- setup ----
  k_rowsq<<<dim3((Bb*Tt)/256), dim3(256), 0, stream>>>(x, x2, Bb*Tt, Dd);
  k_rowsq<<<dim3(Pp/256), dim3(256), 0, stream>>>(prot, p2, Pp, Dd);
  k_transpose<<<dim3(Dd/32, Pp/32), dim3(32,8), 0, stream>>>(prot, pT, Pp, Dd);
  k_bx<<<dim3(G4/256), dim3(256), 0, stream>>>(Wih, blin, bih, bhh, bx);
  k_gemm<0,false><<<dim3(G4/128, Pp/64), dim3(256), 0, stream>>>(Wih, Wlin, Wx, G4, Pp, Hh, nullptr, nullptr, 0);
  k_cvt_bf16<<<dim3((G4*Pp/4)/256), dim3(256), 0, stream>>>(Wx, WxB, G4*Pp/4);

  // ---- main: 4 time-chunks of 128 steps ----
  for (int ch = 0; ch < Tt/TC; ++ch){
    int t0 = ch * TC;
    k_gemm<1,true><<<dim3((Bb*TC)/128, Pp/64), dim3(256), 0, stream>>>(
        x, pT, featsC, Bb*TC, Pp, Dd, x2, p2, t0);
    k_cvt_bf16<<<dim3((Bb*TC*Pp/4)/256), dim3(256), 0, stream>>>(featsC, featsB, Bb*TC*Pp/4);
    k_xs_mfma<<<dim3((Bb*TC)/128, G4/128), dim3(256), 0, stream>>>(
        featsB, WxB, bx, xsC, Bb*TC, G4, Pp);
    void* args[] = { (void*)&Whh, (void*)&xsC, (void*)&cbuf, (void*)&out, (void*)&t0 };
    hipLaunchCooperativeKernel((void*)k_lstm_persist, dim3(NG*WPG), dim3(1024), args, 0, stream);
  }
}

// Round 15
// 3365.740 us; speedup vs baseline: 3.3145x; 3.3145x over previous
//
#include <hip/hip_runtime.h>

#define Bb 32
#define Tt 512
#define Dd 256
#define Pp 512
#define Hh 512
#define G4 2048
#define TC 128   // time-chunk length (4 chunks)
#define NG 8     // batch groups
#define WPG 16   // workgroups per group (grid = 128)
#define NBG 4    // batches per group

__device__ __forceinline__ float sigmf(float x){ return 1.0f/(1.0f+__expf(-x)); }
__device__ __forceinline__ float tanhf_(float x){ return 1.0f - 2.0f/(__expf(2.0f*x)+1.0f); }

typedef __attribute__((ext_vector_type(8))) short v8s;
typedef __attribute__((ext_vector_type(4))) float f32x4;

__device__ __forceinline__ ushort bf16rne(float f){
  uint u = __float_as_uint(f);
  u += 0x7FFF + ((u >> 16) & 1);
  return (ushort)(u >> 16);
}

// out[m] = sum_k A[m,k]^2
__global__ void k_rowsq(const float* __restrict__ A, float* __restrict__ o, int M, int K){
  int m = blockIdx.x*blockDim.x + threadIdx.x;
  if (m >= M) return;
  const float4* a4 = (const float4*)(A + (size_t)m*K);
  float s = 0.f;
  for (int i = 0; i < K/4; ++i){ float4 v = a4[i]; s += v.x*v.x + v.y*v.y + v.z*v.z + v.w*v.w; }
  o[m] = s;
}

// out (N x M) = in (M x N)^T
__global__ void k_transpose(const float* __restrict__ in, float* __restrict__ out, int M, int N){
  __shared__ float tile[32][33];
  int bn = blockIdx.x * 32;
  int bm = blockIdx.y * 32;
  int tx = threadIdx.x, ty = threadIdx.y; // block (32,8)
  #pragma unroll
  for (int i = 0; i < 32; i += 8)
    tile[ty+i][tx] = in[(size_t)(bm+ty+i)*N + bn+tx];
  __syncthreads();
  #pragma unroll
  for (int i = 0; i < 32; i += 8)
    out[(size_t)(bn+ty+i)*M + bm+tx] = tile[tx][ty+i];
}

// bx[r] = dot(W_ih[r,:], b_lin) + b_ih[r] + b_hh[r]
__global__ void k_bx(const float* __restrict__ Wih, const float* __restrict__ blin,
                     const float* __restrict__ bih, const float* __restrict__ bhh,
                     float* __restrict__ bx){
  int r = blockIdx.x*blockDim.x + threadIdx.x; // 2048 threads
  const float4* w4 = (const float4*)(Wih + (size_t)r*Hh);
  const float4* b4 = (const float4*)blin;
  float s = 0.f;
  for (int i = 0; i < Hh/4; ++i){ float4 w=w4[i], b=b4[i]; s += w.x*b.x+w.y*b.y+w.z*b.z+w.w*b.w; }
  bx[r] = s + bih[r] + bhh[r];
}

// Generic tiled fp32 GEMM: C[M,N] = epi(A[M,K] @ B[K,N])
// EPI 0: none. EPI 1: exp(-max(rowAux[m]+colAux[n]-2*acc,0)).
// REMAP: A-row (and rowAux) index m -> (m>>7)*Tt + t0 + (m&127); C stays dense.
// BF16OUT: epilogue converts to bf16 (RNE) and stores ushort4 (fused k_cvt).
template<int EPI, bool REMAP, bool BF16OUT>
__global__ __launch_bounds__(256) void k_gemm(const float* __restrict__ A, const float* __restrict__ Bm,
                                              void* __restrict__ Cv, int M, int N, int K,
                                              const float* __restrict__ rowAux,
                                              const float* __restrict__ colAux, int t0)
{
  __shared__ float As[16][132];
  __shared__ float Bs[16][68];
  const int tid = threadIdx.x;
  const int bm = blockIdx.x * 128;
  const int bn = blockIdx.y * 64;
  const int tm = (tid & 15) * 8;
  const int tn = (tid >> 4) * 4;
  const int arow = tid >> 1;
  const int akq  = (tid & 1) * 8;
  const int brow = tid >> 4;
  const int bcol = (tid & 15) * 4;
  const int am = bm + arow;
  const size_t aRow = REMAP ? ((size_t)(am >> 7) * Tt + t0 + (am & 127)) : (size_t)am;
  float acc[8][4] = {};
  for (int k0 = 0; k0 < K; k0 += 16){
    float4 a0 = *(const float4*)&A[aRow*K + k0 + akq];
    float4 a1 = *(const float4*)&A[aRow*K + k0 + akq + 4];
    float4 bv = *(const float4*)&Bm[(size_t)(k0 + brow)*N + bn + bcol];
    As[akq+0][arow]=a0.x; As[akq+1][arow]=a0.y; As[akq+2][arow]=a0.z; As[akq+3][arow]=a0.w;
    As[akq+4][arow]=a1.x; As[akq+5][arow]=a1.y; As[akq+6][arow]=a1.z; As[akq+7][arow]=a1.w;
    *(float4*)&Bs[brow][bcol] = bv;
    __syncthreads();
    #pragma unroll
    for (int kk = 0; kk < 16; ++kk){
      float4 x0 = *(const float4*)&As[kk][tm];
      float4 x1 = *(const float4*)&As[kk][tm+4];
      float4 y  = *(const float4*)&Bs[kk][tn];
      float av[8] = {x0.x,x0.y,x0.z,x0.w,x1.x,x1.y,x1.z,x1.w};
      #pragma unroll
      for (int i=0;i<8;++i){
        float a = av[i];
        acc[i][0] += a*y.x; acc[i][1] += a*y.y; acc[i][2] += a*y.z; acc[i][3] += a*y.w;
      }
    }
    __syncthreads();
  }
  #pragma unroll
  for (int i=0;i<8;++i){
    int m = bm + tm + i;
    size_t mAux = REMAP ? ((size_t)(m >> 7) * Tt + t0 + (m & 127)) : (size_t)m;
    float vv[4];
    #pragma unroll
    for (int j=0;j<4;++j){
      int n = bn + tn + j;
      float v = acc[i][j];
      if (EPI==1) v = __expf(-fmaxf(rowAux[mAux] + colAux[n] - 2.f*v, 0.f));
      vv[j] = v;
    }
    if (BF16OUT){
      ushort4 o;
      o.x = bf16rne(vv[0]); o.y = bf16rne(vv[1]);
      o.z = bf16rne(vv[2]); o.w = bf16rne(vv[3]);
      *(ushort4*)&((ushort*)Cv)[(size_t)m*N + bn + tn] = o;
    } else {
      float4 o; o.x=vv[0]; o.y=vv[1]; o.z=vv[2]; o.w=vv[3];
      *(float4*)&((float*)Cv)[(size_t)m*N + bn + tn] = o;
    }
  }
}

// xs = feats(bf16)[M,K] @ Wx(bf16)[N,K]^T + bx[N], fp32 out. MFMA 16x16x32.
__global__ __launch_bounds__(256) void k_xs_mfma(
    const ushort* __restrict__ A, const ushort* __restrict__ Bm,
    const float* __restrict__ bx, float* __restrict__ C, int M, int N, int K)
{
  __shared__ ushort As[128][72];
  __shared__ ushort Ws[128][72];
  const int tid  = threadIdx.x;
  const int bm   = blockIdx.x * 128;
  const int bn   = blockIdx.y * 128;
  const int lane = tid & 63;
  const int w    = tid >> 6;
  const int wr   = w >> 1, wc = w & 1;
  const int srow = tid >> 1;
  const int scol = (tid & 1) * 32;
  const int fr   = lane & 15;
  const int fk   = (lane >> 4) * 8;

  f32x4 acc[4][4] = {};

  for (int k0 = 0; k0 < K; k0 += 64){
    const ushort* ag = &A [(size_t)(bm + srow)*K + k0 + scol];
    const ushort* wg = &Bm[(size_t)(bn + srow)*K + k0 + scol];
    #pragma unroll
    for (int q = 0; q < 4; ++q){
      *(v8s*)&As[srow][scol + q*8] = *(const v8s*)&ag[q*8];
      *(v8s*)&Ws[srow][scol + q*8] = *(const v8s*)&wg[q*8];
    }
    __syncthreads();
    #pragma unroll
    for (int kk = 0; kk < 64; kk += 32){
      v8s af[4], bf[4];
      #pragma unroll
      for (int mi = 0; mi < 4; ++mi)
        af[mi] = *(const v8s*)&As[wr*64 + mi*16 + fr][kk + fk];
      #pragma unroll
      for (int ni = 0; ni < 4; ++ni)
        bf[ni] = *(const v8s*)&Ws[wc*64 + ni*16 + fr][kk + fk];
      #pragma unroll
      for (int mi = 0; mi < 4; ++mi)
        #pragma unroll
        for (int ni = 0; ni < 4; ++ni)
          acc[mi][ni] = __builtin_amdgcn_mfma_f32_16x16x32_bf16(af[mi], bf[ni], acc[mi][ni], 0, 0, 0);
    }
    __syncthreads();
  }

  const int cr = lane >> 4;
  #pragma unroll
  for (int ni = 0; ni < 4; ++ni){
    const int n = bn + wc*64 + ni*16 + fr;
    const float bb = bx[n];
    #pragma unroll
    for (int mi = 0; mi < 4; ++mi){
      #pragma unroll
      for (int r = 0; r < 4; ++r){
        const int m = bm + wr*64 + mi*16 + cr*4 + r;
        C[(size_t)m*N + n] = acc[mi][ni][r] + bb;
      }
    }
  }
}

// ============================================================================
// Persistent LSTM — r2/r9-EXACT artifact (measured 775 us/chunk; best e2e
// 3395 us). DO NOT EDIT: every mapping/occupancy/sync deviation tried in
// r3-r8/r14 regressed 1.5-3.5x; 7 sync protocols all land at 775±25.
// Grid: 128 WGs x 512 thr, cooperative. group gid = blockIdx%8 (4 batches),
// wg = blockIdx/8 owns 32 hidden units. W slice: compiler parks in VGPR+AGPR
// (FETCH shows W read once/chunk). Sync: per-group monotonic counter
// (release fetch_add / acquire spin + s_sleep), h via relaxed agent atomics.
// ============================================================================
__global__ __launch_bounds__(512, 2) void k_lstm_persist(
    const float* __restrict__ Whh, const float* __restrict__ xs,
    float* __restrict__ cbuf, float* __restrict__ out,
    unsigned* __restrict__ cnt, int t0)
{
  __shared__ float hbuf[NBG*Hh];   // 8 KB, swizzled
  const int tid  = threadIdx.x;
  const int gid  = blockIdx.x & 7;
  const int wg   = blockIdx.x >> 3;
  const int gsel = tid & 3;
  const int ks   = (tid >> 2) & 15;
  const int ug   = tid >> 6;
  const int jbase = wg*32 + ug*4;

  // ---- load W slice into registers (once per chunk) ----
  float W[4][32];
  #pragma unroll
  for (int r = 0; r < 4; ++r){
    const float* wrow = &Whh[(size_t)(gsel*Hh + jbase + r)*Hh + ks*32];
    #pragma unroll
    for (int c = 0; c < 8; ++c){
      float4 w = *(const float4*)&wrow[c*4];
      W[r][c*4+0]=w.x; W[r][c*4+1]=w.y; W[r][c*4+2]=w.z; W[r][c*4+3]=w.w;
    }
  }

  // this lane's post-reduction output identity
  const int rr = ks >> 2;
  const int bl = ks & 3;
  const int j  = jbase + rr;
  const int b  = gid*NBG + bl;
  float c_st = (t0 == 0) ? 0.f : cbuf[(size_t)b*Hh + j];

  // h-stage assignment
  const int sbl = tid >> 7;           // batch-local 0..3
  const int skb = (tid & 127) * 4;    // k base
  const int ssw = skb ^ (((skb >> 5) & 7) << 2);

  for (int tl = 0; tl < TC; ++tl){
    const int t = t0 + tl;
    // ---- stage h(t-1) into swizzled LDS ----
    float4 hv = {0.f,0.f,0.f,0.f};
    if (t > 0){
      const float* src = &out[((size_t)(gid*NBG + sbl)*Tt + (t-1))*Hh + skb];
      hv.x = __hip_atomic_load(src+0, __ATOMIC_RELAXED, __HIP_MEMORY_SCOPE_AGENT);
      hv.y = __hip_atomic_load(src+1, __ATOMIC_RELAXED, __HIP_MEMORY_SCOPE_AGENT);
      hv.z = __hip_atomic_load(src+2, __ATOMIC_RELAXED, __HIP_MEMORY_SCOPE_AGENT);
      hv.w = __hip_atomic_load(src+3, __ATOMIC_RELAXED, __HIP_MEMORY_SCOPE_AGENT);
    }
    *(float4*)&hbuf[sbl*Hh + ssw] = hv;
    __syncthreads();

    // ---- GEMV: acc[r][bl] += W[r][k] * h[bl][k] over this thread's k-slice ----
    float acc[4][4];
    #pragma unroll
    for (int r=0;r<4;++r){ acc[r][0]=0.f; acc[r][1]=0.f; acc[r][2]=0.f; acc[r][3]=0.f; }
    #pragma unroll
    for (int blq = 0; blq < 4; ++blq){
      const float* hb = &hbuf[blq*Hh + ks*32];
      #pragma unroll
      for (int c = 0; c < 8; ++c){
        float4 h4 = *(const float4*)&hb[(c*4) ^ ((ks & 7) << 2)];
        #pragma unroll
        for (int r = 0; r < 4; ++r){
          acc[r][blq] = fmaf(W[r][c*4+0], h4.x, acc[r][blq]);
          acc[r][blq] = fmaf(W[r][c*4+1], h4.y, acc[r][blq]);
          acc[r][blq] = fmaf(W[r][c*4+2], h4.z, acc[r][blq]);
          acc[r][blq] = fmaf(W[r][c*4+3], h4.w, acc[r][blq]);
        }
      }
    }

    // ---- in-wave reduction over ks (lane bits 2-5) ----
    #pragma unroll
    for (int m = 4; m <= 32; m <<= 1){
      #pragma unroll
      for (int r=0;r<4;++r){
        #pragma unroll
        for (int q=0;q<4;++q)
          acc[r][q] += __shfl_xor(acc[r][q], m, 64);
      }
    }
    // lane ks takes (r=ks>>2, q=ks&3)
    float g = acc[0][0];
    #pragma unroll
    for (int r=0;r<4;++r){
      #pragma unroll
      for (int q=0;q<4;++q)
        if (ks == r*4+q) g = acc[r][q];
    }

    // ---- add xs, collect 4 gates (consecutive lanes), update c,h ----
    g += xs[((size_t)b*TC + tl)*G4 + gsel*Hh + j];
    const int lbase = (tid & 63) & ~3;
    float gi = __shfl(g, lbase+0, 64);
    float gf = __shfl(g, lbase+1, 64);
    float gg = __shfl(g, lbase+2, 64);
    float go = __shfl(g, lbase+3, 64);
    gi = sigmf(gi); gf = sigmf(gf); gg = tanhf_(gg); go = sigmf(go);
    c_st = gf*c_st + gi*gg;
    float h = go * tanhf_(c_st);
    if (gsel == 0)
      __hip_atomic_store(&out[((size_t)b*Tt + t)*Hh + j], h,
                         __ATOMIC_RELAXED, __HIP_MEMORY_SCOPE_AGENT);
    __syncthreads();   // drains vmcnt: all this WG's h-stores complete

    // ---- group barrier: monotonic counter, target uses global step t ----
    if (tid == 0){
      __hip_atomic_fetch_add(&cnt[gid], 1u, __ATOMIC_RELEASE, __HIP_MEMORY_SCOPE_AGENT);
      const unsigned tgt = (unsigned)WPG * (unsigned)(t + 1);
      while (__hip_atomic_load(&cnt[gid], __ATOMIC_ACQUIRE, __HIP_MEMORY_SCOPE_AGENT) < tgt)
        __builtin_amdgcn_s_sleep(1);
    }
    __syncthreads();
  }
  if (gsel == 0) cbuf[(size_t)b*Hh + j] = c_st;
}

extern "C" void kernel_launch(void* const* d_in, const int* in_sizes, int n_in,
                              void* d_out, int out_size, void* d_ws, size_t ws_size,
                              hipStream_t stream)
{
  const float* x    = (const float*)d_in[0];
  const float* prot = (const float*)d_in[1];
  const float* Wlin = (const float*)d_in[2];
  const float* blin = (const float*)d_in[3];
  const float* Wih  = (const float*)d_in[4];
  const float* Whh  = (const float*)d_in[5];
  const float* bih  = (const float*)d_in[6];
  const float* bhh  = (const float*)d_in[7];
  float* out = (float*)d_out;
  float* ws  = (float*)d_ws;

  size_t off = 0;
  auto alloc = [&](size_t n)->float*{ float* p = ws + off; off += (n + 15) & ~((size_t)15); return p; };
  float* x2     = alloc((size_t)Bb*Tt);
  float* p2     = alloc(Pp);
  float* pT     = alloc((size_t)Dd*Pp);
  float* bx     = alloc(G4);
  ushort* WxB   = (ushort*)alloc((size_t)G4*Pp/2);     // bf16, written by fused epilogue
  float* cbuf   = alloc((size_t)Bb*Hh);
  ushort* featsB= (ushort*)alloc((size_t)Bb*TC*Pp/2);  // bf16, written by fused epilogue
  float* xsC    = alloc((size_t)Bb*TC*G4);
  unsigned* cnt = (unsigned*)alloc(16);
  // total ~9.7M floats ~ 39 MB

  // ---- setup ----
  k_rowsq<<<dim3((Bb*Tt)/256), dim3(256), 0, stream>>>(x, x2, Bb*Tt, Dd);
  k_rowsq<<<dim3(Pp/256), dim3(256), 0, stream>>>(prot, p2, Pp, Dd);
  k_transpose<<<dim3(Dd/32, Pp/32), dim3(32,8), 0, stream>>>(prot, pT, Pp, Dd);
  k_bx<<<dim3(G4/256), dim3(256), 0, stream>>>(Wih, blin, bih, bhh, bx);
  // WxB[r,p] = bf16( sum_h W_ih[r,h] * W_lin[h,p] )  — conversion fused
  k_gemm<0,false,true><<<dim3(G4/128, Pp/64), dim3(256), 0, stream>>>(
      Wih, Wlin, WxB, G4, Pp, Hh, nullptr, nullptr, 0);
  hipMemsetAsync(cnt, 0, NG*sizeof(unsigned), stream);

  // ---- main: 4 time-chunks of 128 steps ----
  for (int ch = 0; ch < Tt/TC; ++ch){
    int t0 = ch * TC;
    // feats chunk (RBF epilogue + bf16 store fused)
    k_gemm<1,true,true><<<dim3((Bb*TC)/128, Pp/64), dim3(256), 0, stream>>>(
        x, pT, featsB, Bb*TC, Pp, Dd, x2, p2, t0);
    // xs chunk = featsB @ WxB^T + bx  (MFMA bf16, fp32 accumulate)
    k_xs_mfma<<<dim3((Bb*TC)/128, G4/128), dim3(256), 0, stream>>>(
        featsB, WxB, bx, xsC, Bb*TC, G4, Pp);
    void* args[] = { (void*)&Whh, (void*)&xsC, (void*)&cbuf, (void*)&out, (void*)&cnt, (void*)&t0 };
    hipLaunchCooperativeKernel((void*)k_lstm_persist, dim3(NG*WPG), dim3(512), args, 0, stream);
  }
}